// Round 1
// baseline (413.449 us; speedup 1.0000x reference)
//
#include <hip/hip_runtime.h>
#include <math.h>

#define Bv 2
#define Cc 4
#define Dd 64
#define Hh 192
#define Ww 192
#define HW (Hh*Ww)           // 36864
#define NSLICE (Bv*Dd)       // 128
#define NVOX ((size_t)NSLICE*HW)  // 4718592
#define DHW (Dd*HW)          // 2359296
#define INF_F 1.0e12f

// ---------------- Kernel A: pred / seed-class / presence flags ----------------
// grid: NSLICE*8 blocks of 256; each block does 1/8 of one slice (4608 voxels, 18 iters)
__global__ __launch_bounds__(256) void prep_kernel(const float* __restrict__ inp,
    const int* __restrict__ tgt, unsigned char* __restrict__ pred,
    unsigned char* __restrict__ seed, unsigned int* __restrict__ flags) {
  int part  = blockIdx.x & 7;
  int slice = blockIdx.x >> 3;
  int b = slice >> 6;        // / Dd
  int d = slice & 63;        // % Dd
  const float* base0 = inp + (size_t)(b*Cc)*DHW + (size_t)d*HW;
  const int*   tb    = tgt + (size_t)slice*HW;
  unsigned int lbits = 0;
  int start = part*(HW/8);
  for (int it = 0; it < (HW/8)/256; ++it) {
    int idx = start + it*256 + threadIdx.x;
    float x0 = base0[idx];
    float x1 = base0[DHW + idx];
    float x2 = base0[2*DHW + idx];
    float x3 = base0[3*DHW + idx];
    int p = 0; float best = x0;
    if (x1 > best) { best = x1; p = 1; }
    if (x2 > best) { best = x2; p = 2; }
    if (x3 > best) { best = x3; p = 3; }
    pred[(size_t)slice*HW + idx] = (unsigned char)p;
    int tv = tb[idx];
    if (tv != 0) lbits |= 1u << (tv-1);
    int sc = 0;
    if (tv != 0) {
      int h = idx / Ww, w = idx - h*Ww;
      bool interior = (h > 0) && (h < Hh-1) && (w > 0) && (w < Ww-1)
          && (tb[idx-Ww] == tv) && (tb[idx+Ww] == tv)
          && (tb[idx-1]  == tv) && (tb[idx+1]  == tv);
      if (!interior) sc = tv;   // boundary pixel of its own class
    }
    seed[(size_t)slice*HW + idx] = (unsigned char)sc;
  }
  __shared__ unsigned int sb;
  if (threadIdx.x == 0) sb = 0u;
  __syncthreads();
  if (lbits) atomicOr(&sb, lbits);
  __syncthreads();
  if (threadIdx.x == 0 && sb) atomicOr(&flags[slice], sb);
}

// ---------------- Kernel B: exact nearest-boundary distance + wmap ----------------
// Expanding-ring search: scanning (dr,dc) with dr^2 < best and dr^2+dc^2 < best is
// exhaustive because best only decreases; any seed closer than the final best would
// have been inside the scanned region when reached. Exact EDT semantics.
__global__ __launch_bounds__(256) void edt_kernel(const int* __restrict__ tgt,
    const unsigned char* __restrict__ pred, const unsigned char* __restrict__ seed,
    const unsigned int* __restrict__ flags, float* __restrict__ wmap) {
  int gid = blockIdx.x*256 + threadIdx.x;
  int stride = gridDim.x*256;
  for (size_t v = gid; v < NVOX; v += stride) {
    int slice = (int)(v / HW);
    int idx = (int)(v - (size_t)slice*HW);
    int i = idx / Ww, j = idx - i*Ww;
    int tv = tgt[v];
    int pv = pred[v];
    unsigned int fl = flags[slice];
    const unsigned char* sbuf = seed + (size_t)slice*HW;
    float w = 0.0f;
    #pragma unroll
    for (int c = 1; c <= 3; ++c) {
      bool gc = (tv == c), pc = (pv == c);
      if ((gc != pc) && ((fl >> (c-1)) & 1u)) {
        int best = 1 << 30;
        for (int dr = 0; dr < Hh && dr*dr < best; ++dr) {
          int dr2 = dr*dr;
          for (int s = 0; s < 2; ++s) {
            if (s && dr == 0) continue;
            int r = s ? i + dr : i - dr;
            if (r < 0 || r >= Hh) continue;
            const unsigned char* row = sbuf + r*Ww;
            for (int dc = 0; dc < Ww && dr2 + dc*dc < best; ++dc) {
              bool hit = false;
              int jl = j - dc, jr = j + dc;
              if (jl >= 0 && row[jl] == c) hit = true;
              if (dc && jr < Ww && row[jr] == c) hit = true;
              if (hit) { best = dr2 + dc*dc; break; }
            }
          }
        }
        w += (best == (1 << 30)) ? 1.0e6f : sqrtf((float)best);
      }
    }
    if (((fl & 7u) == 0u) && pv != 0) w += 10.0f;  // empty-slice penalty
    wmap[v] = w;
  }
}

// ---------------- Kernel C: per-slice min/max (non-negative floats -> uint atomics) ----------------
__global__ __launch_bounds__(256) void minmax_kernel(const float* __restrict__ wmap,
    unsigned int* __restrict__ mnb, unsigned int* __restrict__ mxb) {
  int part  = blockIdx.x & 7;
  int slice = blockIdx.x >> 3;
  const float* wb = wmap + (size_t)slice*HW + part*(HW/8);
  float mn = INF_F, mx = 0.0f;
  for (int it = 0; it < (HW/8)/256; ++it) {
    float w = wb[it*256 + threadIdx.x];
    mn = fminf(mn, w); mx = fmaxf(mx, w);
  }
  for (int off = 32; off; off >>= 1) {
    mn = fminf(mn, __shfl_xor(mn, off));
    mx = fmaxf(mx, __shfl_xor(mx, off));
  }
  __shared__ float smn[4], smx[4];
  int wid = threadIdx.x >> 6;
  if ((threadIdx.x & 63) == 0) { smn[wid] = mn; smx[wid] = mx; }
  __syncthreads();
  if (threadIdx.x == 0) {
    mn = fminf(fminf(smn[0], smn[1]), fminf(smn[2], smn[3]));
    mx = fmaxf(fmaxf(smx[0], smx[1]), fmaxf(smx[2], smx[3]));
    atomicMin(&mnb[slice], __float_as_uint(mn));
    atomicMax(&mxb[slice], __float_as_uint(mx));
  }
}

// ---------------- Kernel D: focal * exp(normalized wmap), reduce ----------------
__global__ __launch_bounds__(256) void loss_kernel(const float* __restrict__ inp,
    const int* __restrict__ tgt, const float* __restrict__ wmap,
    const unsigned int* __restrict__ mnb, const unsigned int* __restrict__ mxb,
    float* __restrict__ out) {
  int part  = blockIdx.x & 7;
  int slice = blockIdx.x >> 3;
  int b = slice >> 6, d = slice & 63;
  const float* base0 = inp + (size_t)(b*Cc)*DHW + (size_t)d*HW + part*(HW/8);
  const int*   tb    = tgt + (size_t)slice*HW + part*(HW/8);
  const float* wb    = wmap + (size_t)slice*HW + part*(HW/8);
  float mn = __uint_as_float(mnb[slice]);
  float mx = __uint_as_float(mxb[slice]);
  float inv = 1.0f/(mx - mn + 1e-6f);
  float acc = 0.0f;
  for (int it = 0; it < (HW/8)/256; ++it) {
    int idx = it*256 + threadIdx.x;
    float x0 = base0[idx], x1 = base0[DHW+idx], x2 = base0[2*DHW+idx], x3 = base0[3*DHW+idx];
    int tv = tb[idx];
    float m = fmaxf(fmaxf(x0,x1), fmaxf(x2,x3));
    float e = expf(x0-m)+expf(x1-m)+expf(x2-m)+expf(x3-m);
    float xt = (tv==0) ? x0 : (tv==1) ? x1 : (tv==2) ? x2 : x3;
    float logpt = xt - m - logf(e);
    float pt = expf(logpt);
    float weight = expf((wb[idx]-mn)*inv);
    float omp = 1.0f - pt;
    acc += -(omp*omp)*logpt*weight;
  }
  for (int off = 32; off; off >>= 1) acc += __shfl_xor(acc, off);
  __shared__ float sa[4];
  int wid = threadIdx.x >> 6;
  if ((threadIdx.x & 63) == 0) sa[wid] = acc;
  __syncthreads();
  if (threadIdx.x == 0) atomicAdd(out, sa[0]+sa[1]+sa[2]+sa[3]);
}

extern "C" void kernel_launch(void* const* d_in, const int* in_sizes, int n_in,
                              void* d_out, int out_size, void* d_ws, size_t ws_size,
                              hipStream_t stream) {
  const float* inp = (const float*)d_in[0];
  const int*   tgt = (const int*)d_in[1];
  char* ws = (char*)d_ws;
  unsigned char* pred = (unsigned char*)ws;                 // NVOX bytes
  unsigned char* seed = (unsigned char*)(ws + NVOX);        // NVOX bytes
  float*         wmap = (float*)(ws + 2*NVOX);              // 4*NVOX bytes
  unsigned int* flags = (unsigned int*)(ws + 6*NVOX);       // NSLICE u32
  unsigned int* mxb   = flags + NSLICE;                     // NSLICE u32
  unsigned int* mnb   = mxb + NSLICE;                       // NSLICE u32

  hipMemsetAsync(flags, 0, NSLICE*2*sizeof(unsigned int), stream); // flags + mxb = 0
  hipMemsetAsync(mnb, 0xFF, NSLICE*sizeof(unsigned int), stream);  // mnb = +max uint
  hipMemsetAsync(d_out, 0, sizeof(float), stream);

  prep_kernel<<<NSLICE*8, 256, 0, stream>>>(inp, tgt, pred, seed, flags);
  edt_kernel<<<2048, 256, 0, stream>>>(tgt, pred, seed, flags, wmap);
  minmax_kernel<<<NSLICE*8, 256, 0, stream>>>(wmap, mnb, mxb);
  loss_kernel<<<NSLICE*8, 256, 0, stream>>>(inp, tgt, wmap, mnb, mxb, (float*)d_out);
}